// Round 5
// baseline (166.807 us; speedup 1.0000x reference)
//
#include <hip/hip_runtime.h>
#include <math.h>

// SpectralModule: out[b,c,n,e] = sum_f |rfft13(x[b,c,n,:])[f]|/13 * W[f,e] + b[e]
// x [32,64,128,13] f32, W [7,512] f32, b [512] f32, out [32,64,128,512] f32.
// HBM-write-bound (512 MiB out). All 2048 blocks resident (8/CU).
// R5 changes vs R4: plain (non-NT) dwordx4 stores (fill kernel proves plain
// stores reach 6.7 TB/s); magnitudes read as ds_read_b64 pairs -> 3.5 LDS
// ops/row and a 2-row iteration whose loads batch ahead of 56 FMA + 2 stores.
// VGPR audit: 28 W + 4 bias + 14 mag + 8 acc + ~6 addr ~= 60 < 64 cap.

constexpr int T = 13;
constexpr int F = 7;      // T/2 + 1
constexpr int E = 512;
constexpr int ROWS = 128; // rows per block

typedef float f4 __attribute__((ext_vector_type(4)));
typedef float f2 __attribute__((ext_vector_type(2)));

__global__ __launch_bounds__(256, 8) void spectral_kernel(
    const float* __restrict__ x,
    const float* __restrict__ Wm,
    const float* __restrict__ bias,
    float* __restrict__ out)
{
    // Twiddles fold to inline literals (no memory reads).
    constexpr float CC[T] = {
         1.0f,
         0.8854560256532099f,  0.5680647467311558f,  0.1205366802553230f,
        -0.3546048870425356f, -0.7485107481711011f, -0.9709418174260520f,
        -0.9709418174260520f, -0.7485107481711011f, -0.3546048870425356f,
         0.1205366802553230f,  0.5680647467311558f,  0.8854560256532099f
    };
    constexpr float SS[T] = {
         0.0f,
         0.4647231720437686f,  0.8229838658936564f,  0.9927088740980540f,
         0.9350162426854148f,  0.6631226582407952f,  0.2393156642875578f,
        -0.2393156642875578f, -0.6631226582407952f, -0.9350162426854148f,
        -0.9927088740980540f, -0.8229838658936564f, -0.4647231720437686f
    };

    __shared__ float sx[ROWS * T];    // 6656 B
    __shared__ float smag[F][ROWS];   // 3584 B (transposed: scalar writes
                                      //  conflict-free, b64 broadcast reads)

    const int tid  = threadIdx.x;
    const int lane = tid & 63;
    const int wave = tid >> 6;
    const long long tile_base = (long long)blockIdx.x * ROWS;

    // ---- stage x tile into LDS, coalesced ----
    const float* __restrict__ xg = x + tile_base * T;
#pragma unroll
    for (int k = 0; k < 7; ++k) {
        const int idx = k * 256 + tid;
        if (idx < ROWS * T) sx[idx] = xg[idx];
    }
    __syncthreads();

    // ---- phase 1: two threads per row; live set ~25 VGPR ----
    {
        const int row = tid & 127;
        float xv[T];
#pragma unroll
        for (int t = 0; t < T; ++t) xv[t] = sx[row * T + t];  // stride-13: free

        if (tid < 128) {
            float s = xv[0];
#pragma unroll
            for (int t = 1; t < T; ++t) s += xv[t];
            smag[0][row] = fabsf(s) * (1.0f / 13.0f);
#pragma unroll
            for (int f = 1; f < 4; ++f) {
                float re = xv[0], im = 0.0f;
#pragma unroll
                for (int t = 1; t < T; ++t) {
                    const int k = (f * t) % T;   // compile-time
                    re = fmaf(xv[t], CC[k], re);
                    im = fmaf(xv[t], SS[k], im);
                }
                smag[f][row] = sqrtf(fmaf(re, re, im * im)) * (1.0f / 13.0f);
            }
        } else {
#pragma unroll
            for (int f = 4; f < 7; ++f) {
                float re = xv[0], im = 0.0f;
#pragma unroll
                for (int t = 1; t < T; ++t) {
                    const int k = (f * t) % T;   // compile-time
                    re = fmaf(xv[t], CC[k], re);
                    im = fmaf(xv[t], SS[k], im);
                }
                smag[f][row] = sqrtf(fmaf(re, re, im * im)) * (1.0f / 13.0f);
            }
        }
    }
    __syncthreads();

    // ---- phase 2: W/bias hoist AFTER phase 1 (32 VGPR), then stream ----
    const int c0 = (wave & 1) * 256 + lane * 4;
    f4 wreg[F];
#pragma unroll
    for (int f = 0; f < F; ++f)
        wreg[f] = *reinterpret_cast<const f4*>(Wm + f * E + c0);
    const f4 breg = *reinterpret_cast<const f4*>(bias + c0);

    const int r0 = (wave >> 1) * 64;
    float* __restrict__ obase = out + (tile_base + r0) * (long long)E + c0;

    // Hot loop: 2 rows/iter. 7x ds_read_b64 (broadcast) batch up front,
    // then 56 FMA + 2 plain dwordx4 stores. Never waits on vmcnt.
#pragma unroll 2
    for (int i = 0; i < 32; ++i) {
        f2 m[F];
#pragma unroll
        for (int f = 0; f < F; ++f)
            m[f] = *reinterpret_cast<const f2*>(&smag[f][r0 + 2 * i]);

        f4 a0 = breg, a1 = breg;
#pragma unroll
        for (int f = 0; f < F; ++f) {
            a0.x = fmaf(m[f].x, wreg[f].x, a0.x);
            a0.y = fmaf(m[f].x, wreg[f].y, a0.y);
            a0.z = fmaf(m[f].x, wreg[f].z, a0.z);
            a0.w = fmaf(m[f].x, wreg[f].w, a0.w);
            a1.x = fmaf(m[f].y, wreg[f].x, a1.x);
            a1.y = fmaf(m[f].y, wreg[f].y, a1.y);
            a1.z = fmaf(m[f].y, wreg[f].z, a1.z);
            a1.w = fmaf(m[f].y, wreg[f].w, a1.w);
        }

        *reinterpret_cast<f4*>(obase + (long long)(2 * i) * E)     = a0;
        *reinterpret_cast<f4*>(obase + (long long)(2 * i + 1) * E) = a1;
    }
}

extern "C" void kernel_launch(void* const* d_in, const int* in_sizes, int n_in,
                              void* d_out, int out_size, void* d_ws, size_t ws_size,
                              hipStream_t stream) {
    const float* x = (const float*)d_in[0];
    const float* W = (const float*)d_in[1];
    const float* b = (const float*)d_in[2];
    float* out = (float*)d_out;

    const int nrows = in_sizes[0] / T;      // 262144
    const int blocks = nrows / ROWS;        // 2048 = 8 per CU, all resident

    spectral_kernel<<<blocks, 256, 0, stream>>>(x, W, b, out);
}

// Round 6
// 103.341 us; speedup vs baseline: 1.6142x; 1.6142x over previous
//
#include <hip/hip_runtime.h>
#include <math.h>

// SpectralModule: out[b,c,n,e] = sum_f |rfft13(x[b,c,n,:])[f]|/13 * W[f,e] + b[e]
// x [32,64,128,13] f32, W [7,512] f32, b [512] f32, out [32,64,128,512] f32.
// HBM-write-bound (512 MiB out).
// R6: revert to R4's proven hot-loop ingredients (NT stores, scalar broadcast
// mag reads), change geometry only: each wave owns 64 FULL consecutive rows
// (2 adjacent NT dwordx4 per 2-KiB row -> 128 KiB sequential stream/wave),
// 256 rows/block, 1024 blocks, __launch_bounds__(256,4) -> 128-VGPR cap so
// the ~90-reg live set can never spill (round-2/round-5 failure mode).

constexpr int T = 13;
constexpr int F = 7;      // T/2 + 1
constexpr int E = 512;
constexpr int ROWS = 256; // rows per block

typedef float f4 __attribute__((ext_vector_type(4)));

__global__ __launch_bounds__(256, 4) void spectral_kernel(
    const float* __restrict__ x,
    const float* __restrict__ Wm,
    const float* __restrict__ bias,
    float* __restrict__ out)
{
    // Twiddles fold to inline literals (no memory reads).
    constexpr float CC[T] = {
         1.0f,
         0.8854560256532099f,  0.5680647467311558f,  0.1205366802553230f,
        -0.3546048870425356f, -0.7485107481711011f, -0.9709418174260520f,
        -0.9709418174260520f, -0.7485107481711011f, -0.3546048870425356f,
         0.1205366802553230f,  0.5680647467311558f,  0.8854560256532099f
    };
    constexpr float SS[T] = {
         0.0f,
         0.4647231720437686f,  0.8229838658936564f,  0.9927088740980540f,
         0.9350162426854148f,  0.6631226582407952f,  0.2393156642875578f,
        -0.2393156642875578f, -0.6631226582407952f, -0.9350162426854148f,
        -0.9927088740980540f, -0.8229838658936564f, -0.4647231720437686f
    };

    __shared__ float sx[ROWS * T];    // 13312 B
    __shared__ float smag[F][ROWS];   // 7168 B (transposed: contiguous writes,
                                      //  wave-uniform broadcast reads)

    const int tid  = threadIdx.x;
    const int lane = tid & 63;
    const int wave = tid >> 6;
    const long long tile_base = (long long)blockIdx.x * ROWS;

    // ---- stage x tile into LDS, coalesced (3328 floats = 13 x 256) ----
    const float* __restrict__ xg = x + tile_base * T;
#pragma unroll
    for (int k = 0; k < T; ++k)
        sx[k * 256 + tid] = xg[k * 256 + tid];
    __syncthreads();

    // ---- phase 1: thread r computes all 7 bins of row r ----
    {
        float xv[T];
#pragma unroll
        for (int t = 0; t < T; ++t) xv[t] = sx[tid * T + t];  // 2-way bank = free

        float s = xv[0];
#pragma unroll
        for (int t = 1; t < T; ++t) s += xv[t];
        smag[0][tid] = fabsf(s) * (1.0f / 13.0f);

#pragma unroll
        for (int f = 1; f < F; ++f) {
            float re = xv[0], im = 0.0f;
#pragma unroll
            for (int t = 1; t < T; ++t) {
                const int k = (f * t) % T;   // compile-time
                re = fmaf(xv[t], CC[k], re);
                im = fmaf(xv[t], SS[k], im);
            }
            smag[f][tid] = sqrtf(fmaf(re, re, im * im)) * (1.0f / 13.0f);
        }
    }
    __syncthreads();

    // ---- phase 2: W/bias hoist AFTER phase 1, then sequential stream ----
    // Lane owns cols {4i..4i+3} and {256+4i..256+4i+3}: the wave's two stores
    // cover one contiguous 2-KiB row; consecutive iterations are adjacent rows.
    const int c0 = lane * 4;
    f4 w0[F], w1[F];
#pragma unroll
    for (int f = 0; f < F; ++f) {
        w0[f] = *reinterpret_cast<const f4*>(Wm + f * E + c0);
        w1[f] = *reinterpret_cast<const f4*>(Wm + f * E + 256 + c0);
    }
    const f4 b0 = *reinterpret_cast<const f4*>(bias + c0);
    const f4 b1 = *reinterpret_cast<const f4*>(bias + 256 + c0);

    const int r0 = wave * 64;
    float* __restrict__ obase = out + (tile_base + r0) * (long long)E + c0;

    // Hot loop: 7 broadcast ds_read_b32 + 56 FMA + 2 adjacent NT dwordx4
    // stores per 2-KiB row. Never waits on vmcnt. Live set ~90 < 128 cap.
#pragma unroll 2
    for (int r = 0; r < 64; ++r) {
        f4 a0 = b0, a1 = b1;
#pragma unroll
        for (int f = 0; f < F; ++f) {
            const float m = smag[f][r0 + r];  // wave-uniform -> broadcast
            a0.x = fmaf(m, w0[f].x, a0.x);
            a0.y = fmaf(m, w0[f].y, a0.y);
            a0.z = fmaf(m, w0[f].z, a0.z);
            a0.w = fmaf(m, w0[f].w, a0.w);
            a1.x = fmaf(m, w1[f].x, a1.x);
            a1.y = fmaf(m, w1[f].y, a1.y);
            a1.z = fmaf(m, w1[f].z, a1.z);
            a1.w = fmaf(m, w1[f].w, a1.w);
        }
        __builtin_nontemporal_store(a0, reinterpret_cast<f4*>(obase));
        __builtin_nontemporal_store(a1, reinterpret_cast<f4*>(obase + 256));
        obase += E;
    }
}

extern "C" void kernel_launch(void* const* d_in, const int* in_sizes, int n_in,
                              void* d_out, int out_size, void* d_ws, size_t ws_size,
                              hipStream_t stream) {
    const float* x = (const float*)d_in[0];
    const float* W = (const float*)d_in[1];
    const float* b = (const float*)d_in[2];
    float* out = (float*)d_out;

    const int nrows = in_sizes[0] / T;      // 262144
    const int blocks = nrows / ROWS;        // 1024 = 4 per CU, all resident

    spectral_kernel<<<blocks, 256, 0, stream>>>(x, W, b, out);
}

// Round 8
// 102.815 us; speedup vs baseline: 1.6224x; 1.0051x over previous
//
#include <hip/hip_runtime.h>
#include <math.h>

// SpectralModule: out[b,c,n,e] = sum_f |rfft13(x[b,c,n,:])[f]|/13 * W[f,e] + b[e]
// x [32,64,128,13] f32, W [7,512] f32, b [512] f32, out [32,64,128,512] f32.
// HBM-write-bound (512 MiB out).
// R8 = R7 resubmitted (container died before benching): single-variable A/B
// vs R6 — PLAIN dwordx4 stores instead of NT. (R5's plain-store regression
// was confounded by a VGPR spill; here the live set ~90 sits under the 128
// cap of __launch_bounds__(256,4).) Everything else identical to R6:
// 256 rows/block, 1024 blocks all resident, wave owns 64 full consecutive
// 2-KiB rows -> 128 KiB sequential stream.

constexpr int T = 13;
constexpr int F = 7;      // T/2 + 1
constexpr int E = 512;
constexpr int ROWS = 256; // rows per block

typedef float f4 __attribute__((ext_vector_type(4)));

__global__ __launch_bounds__(256, 4) void spectral_kernel(
    const float* __restrict__ x,
    const float* __restrict__ Wm,
    const float* __restrict__ bias,
    float* __restrict__ out)
{
    // Twiddles fold to inline literals (no memory reads).
    constexpr float CC[T] = {
         1.0f,
         0.8854560256532099f,  0.5680647467311558f,  0.1205366802553230f,
        -0.3546048870425356f, -0.7485107481711011f, -0.9709418174260520f,
        -0.9709418174260520f, -0.7485107481711011f, -0.3546048870425356f,
         0.1205366802553230f,  0.5680647467311558f,  0.8854560256532099f
    };
    constexpr float SS[T] = {
         0.0f,
         0.4647231720437686f,  0.8229838658936564f,  0.9927088740980540f,
         0.9350162426854148f,  0.6631226582407952f,  0.2393156642875578f,
        -0.2393156642875578f, -0.6631226582407952f, -0.9350162426854148f,
        -0.9927088740980540f, -0.8229838658936564f, -0.4647231720437686f
    };

    __shared__ float sx[ROWS * T];    // 13312 B
    __shared__ float smag[F][ROWS];   // 7168 B

    const int tid  = threadIdx.x;
    const int lane = tid & 63;
    const int wave = tid >> 6;
    const long long tile_base = (long long)blockIdx.x * ROWS;

    // ---- stage x tile into LDS, coalesced (3328 floats = 13 x 256) ----
    const float* __restrict__ xg = x + tile_base * T;
#pragma unroll
    for (int k = 0; k < T; ++k)
        sx[k * 256 + tid] = xg[k * 256 + tid];
    __syncthreads();

    // ---- phase 1: thread r computes all 7 bins of row r ----
    {
        float xv[T];
#pragma unroll
        for (int t = 0; t < T; ++t) xv[t] = sx[tid * T + t];  // 2-way bank = free

        float s = xv[0];
#pragma unroll
        for (int t = 1; t < T; ++t) s += xv[t];
        smag[0][tid] = fabsf(s) * (1.0f / 13.0f);

#pragma unroll
        for (int f = 1; f < F; ++f) {
            float re = xv[0], im = 0.0f;
#pragma unroll
            for (int t = 1; t < T; ++t) {
                const int k = (f * t) % T;   // compile-time
                re = fmaf(xv[t], CC[k], re);
                im = fmaf(xv[t], SS[k], im);
            }
            smag[f][tid] = sqrtf(fmaf(re, re, im * im)) * (1.0f / 13.0f);
        }
    }
    __syncthreads();

    // ---- phase 2: W/bias hoist AFTER phase 1, then sequential stream ----
    const int c0 = lane * 4;
    f4 w0[F], w1[F];
#pragma unroll
    for (int f = 0; f < F; ++f) {
        w0[f] = *reinterpret_cast<const f4*>(Wm + f * E + c0);
        w1[f] = *reinterpret_cast<const f4*>(Wm + f * E + 256 + c0);
    }
    const f4 b0 = *reinterpret_cast<const f4*>(bias + c0);
    const f4 b1 = *reinterpret_cast<const f4*>(bias + 256 + c0);

    const int r0 = wave * 64;
    float* __restrict__ obase = out + (tile_base + r0) * (long long)E + c0;

    // Hot loop: 7 broadcast ds_read_b32 + 56 FMA + 2 adjacent PLAIN dwordx4
    // stores per 2-KiB row. Never waits on vmcnt. Live set ~90 < 128 cap.
#pragma unroll 2
    for (int r = 0; r < 64; ++r) {
        f4 a0 = b0, a1 = b1;
#pragma unroll
        for (int f = 0; f < F; ++f) {
            const float m = smag[f][r0 + r];  // wave-uniform -> broadcast
            a0.x = fmaf(m, w0[f].x, a0.x);
            a0.y = fmaf(m, w0[f].y, a0.y);
            a0.z = fmaf(m, w0[f].z, a0.z);
            a0.w = fmaf(m, w0[f].w, a0.w);
            a1.x = fmaf(m, w1[f].x, a1.x);
            a1.y = fmaf(m, w1[f].y, a1.y);
            a1.z = fmaf(m, w1[f].z, a1.z);
            a1.w = fmaf(m, w1[f].w, a1.w);
        }
        *reinterpret_cast<f4*>(obase)       = a0;
        *reinterpret_cast<f4*>(obase + 256) = a1;
        obase += E;
    }
}

extern "C" void kernel_launch(void* const* d_in, const int* in_sizes, int n_in,
                              void* d_out, int out_size, void* d_ws, size_t ws_size,
                              hipStream_t stream) {
    const float* x = (const float*)d_in[0];
    const float* W = (const float*)d_in[1];
    const float* b = (const float*)d_in[2];
    float* out = (float*)d_out;

    const int nrows = in_sizes[0] / T;      // 262144
    const int blocks = nrows / ROWS;        // 1024 = 4 per CU, all resident

    spectral_kernel<<<blocks, 256, 0, stream>>>(x, W, b, out);
}